// Round 3
// baseline (10503.645 us; speedup 1.0000x reference)
//
#include <hip/hip_runtime.h>
#include <hip/hip_bf16.h>
#include <cstdint>

// ---------------------------------------------------------------------------
// B=32, L=2048, E=256, H=128, C=128. Scan steps j=0..2046 (t=j+1).
// cf row for step j uses memory[b, j+2, :]  (cf[:,1:] of reference).
// Chunked precompute (ws-adaptive); (h,c,lp) state persists in ws.
// ROUND 3 FIX: mask arrives as int32 (harness "integer -> const int*"),
// not bytes. Round-2 absmax 2912 == predicted error from byte-reading an
// int32 all-ones mask (1-2 of 6 candidates unmasked -> logp -0.35/step).
// ---------------------------------------------------------------------------
#define JAX_PARTITIONABLE 1   // flip to 0 if idx trajectory mismatches

static constexpr int BB   = 32;
static constexpr int LQ   = 2048;
static constexpr int NSTP = 2047;          // total scan steps
static constexpr int EE   = 256;

// ---------------- Threefry-2x32 (JAX-compatible) ---------------------------
__device__ __forceinline__ uint32_t rotl32(uint32_t x, int d) {
  return (x << d) | (x >> (32 - d));
}
__device__ __forceinline__ void tf2x32(uint32_t k0, uint32_t k1,
                                       uint32_t x0, uint32_t x1,
                                       uint32_t& o0, uint32_t& o1) {
  uint32_t ks2 = k0 ^ k1 ^ 0x1BD11BDAu;
  x0 += k0; x1 += k1;
  x0+=x1; x1=rotl32(x1,13); x1^=x0;  x0+=x1; x1=rotl32(x1,15); x1^=x0;
  x0+=x1; x1=rotl32(x1,26); x1^=x0;  x0+=x1; x1=rotl32(x1, 6); x1^=x0;
  x0+=k1; x1+=ks2+1u;
  x0+=x1; x1=rotl32(x1,17); x1^=x0;  x0+=x1; x1=rotl32(x1,29); x1^=x0;
  x0+=x1; x1=rotl32(x1,16); x1^=x0;  x0+=x1; x1=rotl32(x1,24); x1^=x0;
  x0+=ks2; x1+=k0+2u;
  x0+=x1; x1=rotl32(x1,13); x1^=x0;  x0+=x1; x1=rotl32(x1,15); x1^=x0;
  x0+=x1; x1=rotl32(x1,26); x1^=x0;  x0+=x1; x1=rotl32(x1, 6); x1^=x0;
  x0+=k0; x1+=k1+3u;
  x0+=x1; x1=rotl32(x1,17); x1^=x0;  x0+=x1; x1=rotl32(x1,29); x1^=x0;
  x0+=x1; x1=rotl32(x1,16); x1^=x0;  x0+=x1; x1=rotl32(x1,24); x1^=x0;
  x0+=k1; x1+=ks2+4u;
  x0+=x1; x1=rotl32(x1,13); x1^=x0;  x0+=x1; x1=rotl32(x1,15); x1^=x0;
  x0+=x1; x1=rotl32(x1,26); x1^=x0;  x0+=x1; x1=rotl32(x1, 6); x1^=x0;
  x0+=ks2; x1+=k0+5u;
  o0 = x0; o1 = x1;
}

__device__ __forceinline__ float sigm(float x) { return 1.0f / (1.0f + expf(-x)); }

// ---------------- prep: keys (all steps), Whc = Wih[:,128:]+Whh, bsum ------
__global__ void prep_kernel(const float* __restrict__ Wih,
                            const float* __restrict__ Whh,
                            const float* __restrict__ bih,
                            const float* __restrict__ bhh,
                            uint32_t* __restrict__ keys,
                            float* __restrict__ Whc,
                            float* __restrict__ bsum) {
  int tid = blockIdx.x * blockDim.x + threadIdx.x;
  int nt  = gridDim.x * blockDim.x;
#if JAX_PARTITIONABLE
  for (int i = tid; i < NSTP; i += nt) {
    uint32_t y0, y1;
    tf2x32(0u, 42u, 0u, (uint32_t)i, y0, y1);
    keys[2 * i]     = y0;
    keys[2 * i + 1] = y1;
  }
#else
  for (int x = tid; x < 2 * NSTP; x += nt) {
    int p = (x < NSTP) ? x : x - NSTP;
    uint32_t y0, y1;
    tf2x32(0u, 42u, (uint32_t)p, (uint32_t)(NSTP + p), y0, y1);
    keys[x] = (x < NSTP) ? y0 : y1;
  }
#endif
  for (int p = tid; p < 512 * 128; p += nt) {
    int g = p >> 7, e = p & 127;
    Whc[p] = Wih[g * 256 + 128 + e] + Whh[p];
  }
  for (int p = tid; p < 512; p += nt) bsum[p] = bih[p] + bhh[p];
}

// ---------------- fp32 GEMM: C[m,n] = relu?(bias[n] + A_row(m)·Bm[n,:K]) ---
// MODE 0: A_row = A + m*K
// MODE 1: m = b*NS + cs; A_row = memory + (b*2050 + c0 + cs + 2)*256
#define TM 128
#define TN 128
#define TKK 8
template <int MODE>
__global__ __launch_bounds__(256) void gemm_kernel(
    const float* __restrict__ A, const float* __restrict__ Bm, int ldb,
    const float* __restrict__ bias, float* __restrict__ C, int ldc,
    int M, int K, int relu, int NS, int c0) {
  int m0 = blockIdx.x * TM;
  int n0 = blockIdx.y * TN;
  int tid = threadIdx.x;
  __shared__ float As[TKK][TM + 4];
  __shared__ float Bs[TKK][TN + 4];

  int srow = tid >> 1;
  int skq  = (tid & 1) * 4;
  int gm   = m0 + srow;
  bool mvalid = gm < M;
  const float* Arow;
  if (MODE == 1) {
    int gmc = mvalid ? gm : 0;
    int bb = gmc / NS, cs = gmc % NS;
    Arow = A + (size_t)(bb * (LQ + 2) + c0 + cs + 2) * EE;
  } else {
    Arow = A + (size_t)gm * K;
  }
  const float* Brow = Bm + (size_t)(n0 + srow) * ldb;

  float acc[8][8] = {};
  int tm = (tid >> 4) * 8;
  int tn = (tid & 15) * 8;

  for (int k0 = 0; k0 < K; k0 += TKK) {
    float4 av = mvalid ? *(const float4*)(Arow + k0 + skq)
                       : make_float4(0.f, 0.f, 0.f, 0.f);
    float4 bv = *(const float4*)(Brow + k0 + skq);
    __syncthreads();
    As[skq + 0][srow] = av.x; As[skq + 1][srow] = av.y;
    As[skq + 2][srow] = av.z; As[skq + 3][srow] = av.w;
    Bs[skq + 0][srow] = bv.x; Bs[skq + 1][srow] = bv.y;
    Bs[skq + 2][srow] = bv.z; Bs[skq + 3][srow] = bv.w;
    __syncthreads();
#pragma unroll
    for (int kk = 0; kk < TKK; kk++) {
      float4 a0 = *(const float4*)&As[kk][tm];
      float4 a1 = *(const float4*)&As[kk][tm + 4];
      float4 b0 = *(const float4*)&Bs[kk][tn];
      float4 b1 = *(const float4*)&Bs[kk][tn + 4];
      float aa[8] = {a0.x, a0.y, a0.z, a0.w, a1.x, a1.y, a1.z, a1.w};
      float bb2[8] = {b0.x, b0.y, b0.z, b0.w, b1.x, b1.y, b1.z, b1.w};
#pragma unroll
      for (int i = 0; i < 8; i++)
#pragma unroll
        for (int jx = 0; jx < 8; jx++) acc[i][jx] += aa[i] * bb2[jx];
    }
  }
#pragma unroll
  for (int i = 0; i < 8; i++) {
    int gm2 = m0 + tm + i;
    if (gm2 >= M) break;
#pragma unroll
    for (int jx = 0; jx < 8; jx++) {
      int gn = n0 + tn + jx;
      float v = acc[i][jx] + bias[gn];
      if (relu) v = fmaxf(v, 0.f);
      C[(size_t)gm2 * ldc + gn] = v;
    }
  }
}

// ---------------- sequential scan over one chunk: 1 block per batch --------
// P1 rows: (b*NS+cs)*768 (bp1 folded). G1 rows: (b*NS+cs)*3072 (biases folded)
// state: h[32*128] | c[32*128] | lp[32]
__global__ __launch_bounds__(512, 2) void scan_kernel(
    const float* __restrict__ P1, const float* __restrict__ G1,
    const uint32_t* __restrict__ keys, const int* __restrict__ mask,
    const int* __restrict__ length, const float* __restrict__ Wp1,
    const float* __restrict__ Wp2, const float* __restrict__ bp2,
    const float* __restrict__ Whc, float* __restrict__ state,
    float* __restrict__ out, int c0, int NS, int init) {
  const int b = blockIdx.x;
  const int tid = threadIdx.x;

  __shared__ float h_s[128], c_s[128], hh_s[128];
  __shared__ float sval[768];
  __shared__ float scv[6];
  __shared__ float gates_s[512];
  __shared__ float P1s[2][768];
  __shared__ float EX[2][3072];
  __shared__ float wp2_s[128];
  __shared__ uint32_t klds[2][2];
  __shared__ unsigned char mlds[2][6];
  __shared__ int idx_s;
  __shared__ float lp_s;

  // recurrent weights into registers
  float whc[128];
  {
    const float4* wsrc = (const float4*)(Whc + (size_t)tid * 128);
#pragma unroll
    for (int i = 0; i < 32; i++) {
      float4 v = wsrc[i];
      whc[4 * i] = v.x; whc[4 * i + 1] = v.y;
      whc[4 * i + 2] = v.z; whc[4 * i + 3] = v.w;
    }
  }
  float wp1b[32];
  {
    int m = tid >> 2, q = tid & 3;
    const float4* src = (const float4*)(Wp1 + (size_t)m * 256 + 128 + q * 32);
#pragma unroll
    for (int i = 0; i < 8; i++) {
      float4 v = src[i];
      wp1b[4 * i] = v.x; wp1b[4 * i + 1] = v.y;
      wp1b[4 * i + 2] = v.z; wp1b[4 * i + 3] = v.w;
    }
  }
  if (tid < 128) {
    h_s[tid] = init ? 0.f : state[b * 128 + tid];
    c_s[tid] = init ? 0.f : state[4096 + b * 128 + tid];
    wp2_s[tid] = Wp2[tid];
  }
  if (tid == 0) lp_s = init ? 0.f : state[8192 + b];
  const float bp2v = bp2[0];
  const int len_b = length[b];

  // prologue: stage chunk-step 0
  {
    const size_t r0 = (size_t)b * NS;
    for (int i = tid; i < 192; i += 512)
      ((float4*)P1s[0])[i] = ((const float4*)(P1 + r0 * 768))[i];
    for (int i = tid; i < 768; i += 512)
      ((float4*)EX[0])[i] = ((const float4*)(G1 + r0 * 3072))[i];
    if (tid < 2) klds[0][tid] = keys[2 * c0 + tid];
    if (tid < 6)
      mlds[0][tid] = mask[((size_t)b * LQ + c0 + 1) * 6 + tid] != 0;
  }
  __syncthreads();

  for (int cs = 0; cs < NS; ++cs) {
    const int buf = cs & 1;
    const int j = c0 + cs;
    const int t = j + 1;
    const int csn = (cs + 1 < NS) ? cs + 1 : NS - 1;  // clamped prefetch
    const size_t rn = (size_t)b * NS + csn;

    // prefetch next step's rows (addresses independent of sampling)
    float4 pfA, pfB, pfC;
    uint32_t pfk0 = 0, pfk1 = 0;
    unsigned char pfm = 0;
    if (tid < 192) pfA = ((const float4*)(P1 + rn * 768))[tid];
    pfB = ((const float4*)(G1 + rn * 3072))[tid];
    if (tid < 256) pfC = ((const float4*)(G1 + rn * 3072))[512 + tid];
    if (tid == 384) {
      pfk0 = keys[(c0 + csn) * 2];
      pfk1 = keys[(c0 + csn) * 2 + 1];
    }
    if (tid >= 390 && tid < 396)
      pfm = mask[((size_t)b * LQ + c0 + csn + 1) * 6 + (tid - 390)] != 0;

    // phase 2: hid_h[m] = h · Wp1[m, 128:]
    {
      int m = tid >> 2, q = tid & 3;
      const float4* hq = (const float4*)&h_s[q * 32];
      float s = 0.f;
#pragma unroll
      for (int i = 0; i < 8; i++) {
        float4 hv = hq[i];
        s += wp1b[4 * i] * hv.x + wp1b[4 * i + 1] * hv.y +
             wp1b[4 * i + 2] * hv.z + wp1b[4 * i + 3] * hv.w;
      }
      s += __shfl_xor(s, 1);
      s += __shfl_xor(s, 2);
      if (q == 0) hh_s[m] = s;
    }
    __syncthreads();

    // phase 3: sval[k*128+m] = relu(P1 + hid_h) * Wp2[m]
    for (int p = tid; p < 768; p += 512) {
      int m = p & 127;
      float v = P1s[buf][p] + hh_s[m];
      v = fmaxf(v, 0.f);
      sval[p] = v * wp2_s[m];
    }
    __syncthreads();

    // phase 4: sc[k] = relu(sum_m + bp2)
    {
      int w = tid >> 6, l = tid & 63;
      if (w < 6) {
        float s = sval[w * 128 + l] + sval[w * 128 + 64 + l];
#pragma unroll
        for (int off = 32; off; off >>= 1) s += __shfl_xor(s, off);
        if (l == 0) scv[w] = fmaxf(s + bp2v, 0.f);
      }
    }
    __syncthreads();

    // phase 5: gumbel sampling + log_softmax (wave 0)
    if (tid < 64) {
      float pert = -3.4e38f, logit = -1e9f;
      if (tid < 6) {
        uint32_t y0, y1, bits;
#if JAX_PARTITIONABLE
        tf2x32(klds[buf][0], klds[buf][1], 0u, (uint32_t)(b * 6 + tid), y0, y1);
        bits = y0 ^ y1;
#else
        int i6 = b * 6 + tid;
        int p = (i6 < 96) ? i6 : i6 - 96;
        tf2x32(klds[buf][0], klds[buf][1], (uint32_t)p, (uint32_t)(96 + p), y0, y1);
        bits = (i6 < 96) ? y0 : y1;
#endif
        float f = __uint_as_float((bits >> 9) | 0x3f800000u) - 1.0f;
        float u = fmaxf(f, 1.17549435e-38f);
        double g = -log(-log((double)u));
        logit = mlds[buf][tid] ? scv[tid] : -1e9f;
        pert = (float)g + logit;
      }
      int idx = 0;
      float best = __shfl(pert, 0);
#pragma unroll
      for (int k = 1; k < 6; k++) {
        float pk = __shfl(pert, k);
        if (pk > best) { best = pk; idx = k; }
      }
      float mx = __shfl(logit, 0);
#pragma unroll
      for (int k = 1; k < 6; k++) mx = fmaxf(mx, __shfl(logit, k));
      float ssum = 0.f;
#pragma unroll
      for (int k = 0; k < 6; k++) ssum += expf(__shfl(logit, k) - mx);
      if (tid == 0) {
        float li = __shfl(logit, idx);
        float logp = li - mx - logf(ssum);
        if (len_b > t) lp_s += logp;
        idx_s = idx;
        out[32 + (size_t)j * 32 + b] = (float)idx;
      }
    }
    __syncthreads();

    // phase 6: gates[g] = G1[chosen][g] + h · Whc[g,:]
    {
      const int g = tid;
      float acc = EX[buf][idx_s * 512 + g];
      const float4* hv4 = (const float4*)h_s;
#pragma unroll
      for (int i = 0; i < 32; i++) {
        float4 hv = hv4[i];
        acc += whc[4 * i] * hv.x + whc[4 * i + 1] * hv.y +
               whc[4 * i + 2] * hv.z + whc[4 * i + 3] * hv.w;
      }
      gates_s[g] = acc;
    }
    __syncthreads();

    // phase 7: LSTM pointwise + park prefetched data
    if (tid < 128) {
      float iv = gates_s[tid], fv = gates_s[128 + tid];
      float gv = gates_s[256 + tid], ov = gates_s[384 + tid];
      float c2 = sigm(fv) * c_s[tid] + sigm(iv) * tanhf(gv);
      float h2 = sigm(ov) * tanhf(c2);
      c_s[tid] = c2;
      h_s[tid] = h2;
    }
    {
      int nb = buf ^ 1;
      if (tid < 192) ((float4*)P1s[nb])[tid] = pfA;
      ((float4*)EX[nb])[tid] = pfB;
      if (tid < 256) ((float4*)EX[nb])[512 + tid] = pfC;
      if (tid == 384) { klds[nb][0] = pfk0; klds[nb][1] = pfk1; }
      if (tid >= 390 && tid < 396) mlds[nb][tid - 390] = pfm;
    }
    __syncthreads();
  }

  // epilogue: persist state, write log_probs (final chunk's value survives)
  if (tid < 128) {
    state[b * 128 + tid] = h_s[tid];
    state[4096 + b * 128 + tid] = c_s[tid];
  }
  if (tid == 0) {
    state[8192 + b] = lp_s;
    out[b] = lp_s;
  }
}

__global__ void sentinel_kernel(float* out, int n, float val) {
  int i = blockIdx.x * blockDim.x + threadIdx.x;
  if (i < n) out[i] = val;
}

// ---------------------------------------------------------------------------
extern "C" void kernel_launch(void* const* d_in, const int* in_sizes, int n_in,
                              void* d_out, int out_size, void* d_ws,
                              size_t ws_size, hipStream_t stream) {
  const float* memory = (const float*)d_in[0];
  const int* mask = (const int*)d_in[1];     // bool delivered as int32
  const int* length = (const int*)d_in[2];
  const float* W1  = (const float*)d_in[3];
  const float* b1  = (const float*)d_in[4];
  const float* Wp1 = (const float*)d_in[5];
  const float* bp1 = (const float*)d_in[6];
  const float* Wp2 = (const float*)d_in[7];
  const float* bp2 = (const float*)d_in[8];
  const float* Wih = (const float*)d_in[9];
  const float* Whh = (const float*)d_in[10];
  const float* bih = (const float*)d_in[11];
  const float* bhh = (const float*)d_in[12];
  float* out = (float*)d_out;

  // fixed ws blocks
  char* ws = (char*)d_ws;
  const size_t o_keys  = 0;                      // 2047*2*4 -> 16384
  const size_t o_whc   = 16384;                  // 262144
  const size_t o_bsum  = o_whc + 262144;         // 2048
  const size_t o_state = o_bsum + 2048;          // 33KB -> pad to 36864
  const size_t o_buf   = o_state + 36864;        // chunk buffers start

  // per-step-of-chunk cost: 32 * (768 cf + 768 P1 + 3072 G1) * 4B
  const size_t per_cs = 32ull * (768 + 768 + 3072) * 4;  // 589824
  long long usable = (long long)ws_size - (long long)o_buf;
  int CS = (usable > 0) ? (int)(usable / (long long)per_cs) : 0;
  if (CS > NSTP) CS = NSTP;
  if (CS < 1) {
    float val = -100000.0f - (float)(ws_size >> 20);  // encode ws MB
    sentinel_kernel<<<(out_size + 255) / 256, 256, 0, stream>>>(out, out_size, val);
    return;
  }

  uint32_t* keys = (uint32_t*)(ws + o_keys);
  float* Whc   = (float*)(ws + o_whc);
  float* bsum  = (float*)(ws + o_bsum);
  float* state = (float*)(ws + o_state);

  prep_kernel<<<64, 256, 0, stream>>>(Wih, Whh, bih, bhh, keys, Whc, bsum);

  int nchunks = (NSTP + CS - 1) / CS;
  for (int c = 0; c < nchunks; ++c) {
    int c0 = c * CS;
    int NS = (c0 + CS <= NSTP) ? CS : (NSTP - c0);
    int Mcf = 32 * NS;        // cf rows this chunk
    int M6  = Mcf * 6;        // candidate rows this chunk

    float* cf = (float*)(ws + o_buf);
    float* P1 = cf + (size_t)Mcf * 768;
    float* G1 = P1 + (size_t)M6 * 128;

    // cf = relu(memory_rows @ W1^T + b1): M=32*NS, N=768, K=256
    gemm_kernel<1><<<dim3((Mcf + TM - 1) / TM, 768 / TN), 256, 0, stream>>>(
        memory, W1, 256, b1, cf, 768, Mcf, 256, 1, NS, c0);
    // P1 = cf6 @ Wp1[:, :128]^T + bp1: M=M6, N=128, K=128
    gemm_kernel<0><<<dim3((M6 + TM - 1) / TM, 128 / TN), 256, 0, stream>>>(
        cf, Wp1, 256, bp1, P1, 128, M6, 128, 0, NS, c0);
    // G1 = cf6 @ Wih[:, :128]^T + (bih+bhh): M=M6, N=512, K=128
    gemm_kernel<0><<<dim3((M6 + TM - 1) / TM, 512 / TN), 256, 0, stream>>>(
        cf, Wih, 256, bsum, G1, 512, M6, 512, 0, NS, c0);
    // scan this chunk
    scan_kernel<<<BB, 512, 0, stream>>>(P1, G1, keys, mask, length, Wp1, Wp2,
                                        bp2, Whc, state, out, c0, NS,
                                        (c == 0) ? 1 : 0);
  }
}

// Round 4
// 5756.793 us; speedup vs baseline: 1.8246x; 1.8246x over previous
//
#include <hip/hip_runtime.h>
#include <hip/hip_bf16.h>
#include <cstdint>

// ---------------------------------------------------------------------------
// B=32, L=2048, E=256, H=128, C=128. Scan steps j=0..2046 (t=j+1).
// cf row for step j uses memory[b, j+2, :].
// R4: scan restructured — h read once/step (padded quarters), h·Whc hoisted
// before sampling, gumbels precomputed, raw lgkm-only barriers (prefetch
// stays in flight), idx batched. P1+G1 GEMMs fused (N=640).
// ---------------------------------------------------------------------------
static constexpr int BB   = 32;
static constexpr int LQ   = 2048;
static constexpr int NSTP = 2047;
static constexpr int EE   = 256;

__device__ __forceinline__ void bar_lds() {
  asm volatile("s_waitcnt lgkmcnt(0)\n\ts_barrier" ::: "memory");
}

// ---------------- Threefry-2x32 (JAX-compatible, verified by R3 pass) ------
__device__ __forceinline__ uint32_t rotl32(uint32_t x, int d) {
  return (x << d) | (x >> (32 - d));
}
__device__ __forceinline__ void tf2x32(uint32_t k0, uint32_t k1,
                                       uint32_t x0, uint32_t x1,
                                       uint32_t& o0, uint32_t& o1) {
  uint32_t ks2 = k0 ^ k1 ^ 0x1BD11BDAu;
  x0 += k0; x1 += k1;
  x0+=x1; x1=rotl32(x1,13); x1^=x0;  x0+=x1; x1=rotl32(x1,15); x1^=x0;
  x0+=x1; x1=rotl32(x1,26); x1^=x0;  x0+=x1; x1=rotl32(x1, 6); x1^=x0;
  x0+=k1; x1+=ks2+1u;
  x0+=x1; x1=rotl32(x1,17); x1^=x0;  x0+=x1; x1=rotl32(x1,29); x1^=x0;
  x0+=x1; x1=rotl32(x1,16); x1^=x0;  x0+=x1; x1=rotl32(x1,24); x1^=x0;
  x0+=ks2; x1+=k0+2u;
  x0+=x1; x1=rotl32(x1,13); x1^=x0;  x0+=x1; x1=rotl32(x1,15); x1^=x0;
  x0+=x1; x1=rotl32(x1,26); x1^=x0;  x0+=x1; x1=rotl32(x1, 6); x1^=x0;
  x0+=k0; x1+=k1+3u;
  x0+=x1; x1=rotl32(x1,17); x1^=x0;  x0+=x1; x1=rotl32(x1,29); x1^=x0;
  x0+=x1; x1=rotl32(x1,16); x1^=x0;  x0+=x1; x1=rotl32(x1,24); x1^=x0;
  x0+=k1; x1+=ks2+4u;
  x0+=x1; x1=rotl32(x1,13); x1^=x0;  x0+=x1; x1=rotl32(x1,15); x1^=x0;
  x0+=x1; x1=rotl32(x1,26); x1^=x0;  x0+=x1; x1=rotl32(x1, 6); x1^=x0;
  x0+=ks2; x1+=k0+5u;
  o0 = x0; o1 = x1;
}

__device__ __forceinline__ float sigm(float x) { return 1.0f / (1.0f + expf(-x)); }

// ---------------- prep: Whc = Wih[:,128:]+Whh; Wcomb/cbias (P1|G1 fused) ---
__global__ void prep_kernel(const float* __restrict__ Wp1,
                            const float* __restrict__ bp1,
                            const float* __restrict__ Wih,
                            const float* __restrict__ Whh,
                            const float* __restrict__ bih,
                            const float* __restrict__ bhh,
                            float* __restrict__ Whc,
                            float* __restrict__ Wcomb,
                            float* __restrict__ cbias) {
  int tid = blockIdx.x * blockDim.x + threadIdx.x;
  int nt  = gridDim.x * blockDim.x;
  for (int p = tid; p < 512 * 128; p += nt) {
    int g = p >> 7, e = p & 127;
    Whc[p] = Wih[g * 256 + 128 + e] + Whh[p];
  }
  for (int p = tid; p < 640 * 128; p += nt) {
    int n = p >> 7, e = p & 127;
    Wcomb[p] = (n < 128) ? Wp1[n * 256 + e] : Wih[(n - 128) * 256 + e];
  }
  for (int n = tid; n < 640; n += nt)
    cbias[n] = (n < 128) ? bp1[n] : (bih[n - 128] + bhh[n - 128]);
}

// ---------------- precompute gumbel perturbations pg[j][b*6+k] -------------
__global__ void gumbel_kernel(float* __restrict__ pg) {
  int idx = blockIdx.x * blockDim.x + threadIdx.x;
  if (idx >= NSTP * 192) return;
  int j = idx / 192, r = idx % 192;
  uint32_t a0, a1, y0, y1;
  tf2x32(0u, 42u, 0u, (uint32_t)j, a0, a1);          // key_j = split(key42)[j]
  tf2x32(a0, a1, 0u, (uint32_t)r, y0, y1);           // bits for (b,k)
  uint32_t bits = y0 ^ y1;
  float f = __uint_as_float((bits >> 9) | 0x3f800000u) - 1.0f;
  float u = fmaxf(f, 1.17549435e-38f);
  double g = -log(-log((double)u));
  pg[idx] = (float)g;
}

// ---------------- fp32 GEMM (unchanged from R3) ----------------------------
#define TM 128
#define TN 128
#define TKK 8
template <int MODE>
__global__ __launch_bounds__(256) void gemm_kernel(
    const float* __restrict__ A, const float* __restrict__ Bm, int ldb,
    const float* __restrict__ bias, float* __restrict__ C, int ldc,
    int M, int K, int relu, int NS, int c0) {
  int m0 = blockIdx.x * TM;
  int n0 = blockIdx.y * TN;
  int tid = threadIdx.x;
  __shared__ float As[TKK][TM + 4];
  __shared__ float Bs[TKK][TN + 4];

  int srow = tid >> 1;
  int skq  = (tid & 1) * 4;
  int gm   = m0 + srow;
  bool mvalid = gm < M;
  const float* Arow;
  if (MODE == 1) {
    int gmc = mvalid ? gm : 0;
    int bb = gmc / NS, cs = gmc % NS;
    Arow = A + (size_t)(bb * (LQ + 2) + c0 + cs + 2) * EE;
  } else {
    Arow = A + (size_t)gm * K;
  }
  const float* Brow = Bm + (size_t)(n0 + srow) * ldb;

  float acc[8][8] = {};
  int tm = (tid >> 4) * 8;
  int tn = (tid & 15) * 8;

  for (int k0 = 0; k0 < K; k0 += TKK) {
    float4 av = mvalid ? *(const float4*)(Arow + k0 + skq)
                       : make_float4(0.f, 0.f, 0.f, 0.f);
    float4 bv = *(const float4*)(Brow + k0 + skq);
    __syncthreads();
    As[skq + 0][srow] = av.x; As[skq + 1][srow] = av.y;
    As[skq + 2][srow] = av.z; As[skq + 3][srow] = av.w;
    Bs[skq + 0][srow] = bv.x; Bs[skq + 1][srow] = bv.y;
    Bs[skq + 2][srow] = bv.z; Bs[skq + 3][srow] = bv.w;
    __syncthreads();
#pragma unroll
    for (int kk = 0; kk < TKK; kk++) {
      float4 a0 = *(const float4*)&As[kk][tm];
      float4 a1 = *(const float4*)&As[kk][tm + 4];
      float4 b0 = *(const float4*)&Bs[kk][tn];
      float4 b1 = *(const float4*)&Bs[kk][tn + 4];
      float aa[8] = {a0.x, a0.y, a0.z, a0.w, a1.x, a1.y, a1.z, a1.w};
      float bb2[8] = {b0.x, b0.y, b0.z, b0.w, b1.x, b1.y, b1.z, b1.w};
#pragma unroll
      for (int i = 0; i < 8; i++)
#pragma unroll
        for (int jx = 0; jx < 8; jx++) acc[i][jx] += aa[i] * bb2[jx];
    }
  }
#pragma unroll
  for (int i = 0; i < 8; i++) {
    int gm2 = m0 + tm + i;
    if (gm2 >= M) break;
#pragma unroll
    for (int jx = 0; jx < 8; jx++) {
      int gn = n0 + tn + jx;
      float v = acc[i][jx] + bias[gn];
      if (relu) v = fmaxf(v, 0.f);
      C[(size_t)gm2 * ldc + gn] = v;
    }
  }
}

// ---------------- scan v2: 4 phases, 4 raw barriers, h·Whc hoisted ---------
// exf rows per (b,cs): 6 candidates x [p1(128) | g1(512)] = 3840 floats.
// state: h[32*128] | c[32*128] | lp[32]
__global__ __launch_bounds__(512) void scan2_kernel(
    const float* __restrict__ exf, const float* __restrict__ pg,
    const int* __restrict__ mask, const int* __restrict__ length,
    const float* __restrict__ Wp1, const float* __restrict__ Wp2,
    const float* __restrict__ bp2, const float* __restrict__ Whc,
    float* __restrict__ state, float* __restrict__ out,
    int c0, int NS, int init) {
  const int b = blockIdx.x;
  const int tid = threadIdx.x;
  const int q = tid & 3;        // h-quarter owned for dot products
  const int gb = tid >> 2;      // 0..127: Wp1 row / gate base

  __shared__ float EXF[2][3840];
  __shared__ float h_pad[144];      // quarters at stride 36 (bank-spread)
  __shared__ float hh_s[128];
  __shared__ float ghh_s[512];
  __shared__ float scv[8];
  __shared__ float gum_lds[2][8];
  __shared__ int   msk_lds[2][8];
  __shared__ int   idx_s;
  __shared__ char  idxb[2048];

  // ---- weights into registers: Wp1[gb,128+q*32..] and Whc[gb+128k, q*32..]
  float4 wp1r4[8], wv40[8], wv41[8], wv42[8], wv43[8];
  {
    const float4* s0 = (const float4*)(Wp1 + (size_t)gb * 256 + 128 + q * 32);
    const float4* a0 = (const float4*)(Whc + ((size_t)gb + 0) * 128 + q * 32);
    const float4* a1 = (const float4*)(Whc + ((size_t)gb + 128) * 128 + q * 32);
    const float4* a2 = (const float4*)(Whc + ((size_t)gb + 256) * 128 + q * 32);
    const float4* a3 = (const float4*)(Whc + ((size_t)gb + 384) * 128 + q * 32);
#pragma unroll
    for (int i = 0; i < 8; i++) {
      wp1r4[i] = s0[i];
      wv40[i] = a0[i]; wv41[i] = a1[i]; wv42[i] = a2[i]; wv43[i] = a3[i];
    }
  }
  const int l64 = tid & 63;
  const float wp2a = Wp2[l64], wp2b = Wp2[64 + l64];
  const float bp2v = bp2[0];
  const int len_b = length[b];

  float c_r = 0.f, lp_r = 0.f;
  if (tid < 144) h_pad[tid] = 0.f;
  if (tid < 128) {
    if (!init) h_pad[(tid >> 5) * 36 + (tid & 31)] = state[b * 128 + tid];
    c_r = init ? 0.f : state[4096 + b * 128 + tid];
  }
  if (tid == 0) lp_r = init ? 0.f : state[8192 + b];

  // ---- prologue: stage step 0, issue prefetch for step 1
  float4 pfE0, pfE1;
  float pfg = 0.f; int pfm = 0;
  {
    const float4* e0 = (const float4*)(exf + (size_t)b * NS * 3840);
    ((float4*)EXF[0])[tid] = e0[tid];
    if (tid < 448) ((float4*)EXF[0])[512 + tid] = e0[512 + tid];
    if (tid < 6) {
      gum_lds[0][tid] = pg[(size_t)c0 * 192 + b * 6 + tid];
      msk_lds[0][tid] = mask[((size_t)b * LQ + c0 + 1) * 6 + tid];
    }
    int cs1 = (NS > 1) ? 1 : 0;
    const float4* e1 = (const float4*)(exf + ((size_t)b * NS + cs1) * 3840);
    pfE0 = e1[tid];
    if (tid < 448) pfE1 = e1[512 + tid];
    if (tid < 6) {
      pfg = pg[(size_t)(c0 + cs1) * 192 + b * 6 + tid];
      pfm = mask[((size_t)b * LQ + c0 + cs1 + 1) * 6 + tid];
    }
  }
  bar_lds();

  for (int cs = 0; cs < NS; ++cs) {
    const int buf = cs & 1;

    // ---- phase A: h once from LDS; hid_h partial + gate-h partials
    {
      const float4* hp4 = (const float4*)(h_pad + q * 36);
      float hidp = 0.f, p0 = 0.f, p1 = 0.f, p2 = 0.f, p3 = 0.f;
#pragma unroll
      for (int i = 0; i < 8; i++) {
        float4 hv = hp4[i];
        float4 w = wp1r4[i];
        hidp += w.x * hv.x + w.y * hv.y + w.z * hv.z + w.w * hv.w;
        float4 a = wv40[i];
        p0 += a.x * hv.x + a.y * hv.y + a.z * hv.z + a.w * hv.w;
        a = wv41[i];
        p1 += a.x * hv.x + a.y * hv.y + a.z * hv.z + a.w * hv.w;
        a = wv42[i];
        p2 += a.x * hv.x + a.y * hv.y + a.z * hv.z + a.w * hv.w;
        a = wv43[i];
        p3 += a.x * hv.x + a.y * hv.y + a.z * hv.z + a.w * hv.w;
      }
      hidp += __shfl_xor(hidp, 1); hidp += __shfl_xor(hidp, 2);
      p0 += __shfl_xor(p0, 1); p0 += __shfl_xor(p0, 2);
      p1 += __shfl_xor(p1, 1); p1 += __shfl_xor(p1, 2);
      p2 += __shfl_xor(p2, 1); p2 += __shfl_xor(p2, 2);
      p3 += __shfl_xor(p3, 1); p3 += __shfl_xor(p3, 2);
      if (q == 0) {
        hh_s[gb] = hidp;
        ghh_s[gb] = p0; ghh_s[128 + gb] = p1;
        ghh_s[256 + gb] = p2; ghh_s[384 + gb] = p3;
      }
    }
    bar_lds();

    // ---- phase B: sc[k] for 6 candidates (wave k)
    {
      int w = tid >> 6;
      if (w < 6) {
        float v1 = fmaxf(EXF[buf][w * 640 + l64] + hh_s[l64], 0.f) * wp2a;
        float v2 = fmaxf(EXF[buf][w * 640 + 64 + l64] + hh_s[64 + l64], 0.f) * wp2b;
        float s = v1 + v2;
#pragma unroll
        for (int off = 32; off; off >>= 1) s += __shfl_xor(s, off);
        if (l64 == 0) scv[w] = fmaxf(s + bp2v, 0.f);
      }
    }
    bar_lds();

    // ---- phase C: sampling + logp (wave 0)
    if (tid < 64) {
      float pert = -3.4e38f, logit = -1e9f;
      if (tid < 6) {
        logit = msk_lds[buf][tid] ? scv[tid] : -1e9f;
        pert = gum_lds[buf][tid] + logit;
      }
      int idx = 0;
      float best = __shfl(pert, 0);
#pragma unroll
      for (int k = 1; k < 6; k++) {
        float pk = __shfl(pert, k);
        if (pk > best) { best = pk; idx = k; }
      }
      float mx = __shfl(logit, 0);
#pragma unroll
      for (int k = 1; k < 6; k++) mx = fmaxf(mx, __shfl(logit, k));
      float ssum = 0.f;
#pragma unroll
      for (int k = 0; k < 6; k++) ssum += expf(__shfl(logit, k) - mx);
      if (tid == 0) {
        float li = __shfl(logit, idx);
        float logp = li - mx - logf(ssum);
        if (len_b > c0 + cs + 1) lp_r += logp;
        idx_s = idx;
        idxb[cs] = (char)idx;
      }
    }
    bar_lds();

    // ---- phase D: LSTM pointwise (waves 0-1) | park + issue prefetch (all)
    if (tid < 128) {
      int base = idx_s * 640 + 128 + tid;
      float iv = EXF[buf][base] + ghh_s[tid];
      float fv = EXF[buf][base + 128] + ghh_s[128 + tid];
      float gg = EXF[buf][base + 256] + ghh_s[256 + tid];
      float ov = EXF[buf][base + 384] + ghh_s[384 + tid];
      float c2 = sigm(fv) * c_r + sigm(iv) * tanhf(gg);
      float h2 = sigm(ov) * tanhf(c2);
      c_r = c2;
      h_pad[(tid >> 5) * 36 + (tid & 31)] = h2;
    }
    {
      int nb = buf ^ 1;
      ((float4*)EXF[nb])[tid] = pfE0;
      if (tid < 448) ((float4*)EXF[nb])[512 + tid] = pfE1;
      if (tid < 6) { gum_lds[nb][tid] = pfg; msk_lds[nb][tid] = pfm; }
      int csp = (cs + 2 < NS) ? cs + 2 : NS - 1;
      const float4* en = (const float4*)(exf + ((size_t)b * NS + csp) * 3840);
      pfE0 = en[tid];
      if (tid < 448) pfE1 = en[512 + tid];
      if (tid < 6) {
        pfg = pg[(size_t)(c0 + csp) * 192 + b * 6 + tid];
        pfm = mask[((size_t)b * LQ + c0 + csp + 1) * 6 + tid];
      }
    }
    bar_lds();
  }

  // ---- epilogue
  if (tid < 128) {
    state[b * 128 + tid] = h_pad[(tid >> 5) * 36 + (tid & 31)];
    state[4096 + b * 128 + tid] = c_r;
  }
  if (tid == 0) {
    state[8192 + b] = lp_r;
    out[b] = lp_r;
  }
  for (int i = tid; i < NS; i += 512)
    out[32 + (size_t)(c0 + i) * 32 + b] = (float)idxb[i];
}

__global__ void sentinel_kernel(float* out, int n, float val) {
  int i = blockIdx.x * blockDim.x + threadIdx.x;
  if (i < n) out[i] = val;
}

// ---------------------------------------------------------------------------
extern "C" void kernel_launch(void* const* d_in, const int* in_sizes, int n_in,
                              void* d_out, int out_size, void* d_ws,
                              size_t ws_size, hipStream_t stream) {
  const float* memory = (const float*)d_in[0];
  const int* mask = (const int*)d_in[1];     // bool delivered as int32
  const int* length = (const int*)d_in[2];
  const float* W1  = (const float*)d_in[3];
  const float* b1  = (const float*)d_in[4];
  const float* Wp1 = (const float*)d_in[5];
  const float* bp1 = (const float*)d_in[6];
  const float* Wp2 = (const float*)d_in[7];
  const float* bp2 = (const float*)d_in[8];
  const float* Wih = (const float*)d_in[9];
  const float* Whh = (const float*)d_in[10];
  const float* bih = (const float*)d_in[11];
  const float* bhh = (const float*)d_in[12];
  float* out = (float*)d_out;

  char* ws = (char*)d_ws;
  const size_t o_whc   = 0;                    // 512*128*4  = 262144
  const size_t o_wcomb = 262144;               // 640*128*4  = 327680
  const size_t o_cbias = 589824;               // 640*4      = 2560
  const size_t o_state = 592384;               // 8224*4 -> pad 36864
  const size_t o_pg    = 629248;               // 2047*192*4 = 1572096
  const size_t o_buf   = 2201344;              // chunk buffers

  // per-step-of-chunk: 32 * (768 cf + 3840 exf) * 4B
  const size_t per_cs = 32ull * (768 + 3840) * 4;  // 589824
  long long usable = (long long)ws_size - (long long)o_buf;
  int CS = (usable > 0) ? (int)(usable / (long long)per_cs) : 0;
  if (CS > NSTP) CS = NSTP;
  if (CS < 1) {
    float val = -100000.0f - (float)(ws_size >> 20);
    sentinel_kernel<<<(out_size + 255) / 256, 256, 0, stream>>>(out, out_size, val);
    return;
  }

  float* Whc   = (float*)(ws + o_whc);
  float* Wcomb = (float*)(ws + o_wcomb);
  float* cbias = (float*)(ws + o_cbias);
  float* state = (float*)(ws + o_state);
  float* pgbuf = (float*)(ws + o_pg);

  prep_kernel<<<64, 256, 0, stream>>>(Wp1, bp1, Wih, Whh, bih, bhh,
                                      Whc, Wcomb, cbias);
  gumbel_kernel<<<(NSTP * 192 + 255) / 256, 256, 0, stream>>>(pgbuf);

  int nchunks = (NSTP + CS - 1) / CS;
  for (int c = 0; c < nchunks; ++c) {
    int c0 = c * CS;
    int NS = (c0 + CS <= NSTP) ? CS : (NSTP - c0);
    int Mcf = 32 * NS;
    int M6  = Mcf * 6;

    float* cf  = (float*)(ws + o_buf);
    float* exf = cf + (size_t)Mcf * 768;

    // cf = relu(memory_rows @ W1^T + b1): M=32*NS, N=768, K=256
    gemm_kernel<1><<<dim3((Mcf + TM - 1) / TM, 768 / TN), 256, 0, stream>>>(
        memory, W1, 256, b1, cf, 768, Mcf, 256, 1, NS, c0);
    // exf = cf6 @ Wcomb^T + cbias: M=M6, N=640 (p1|g1), K=128
    gemm_kernel<0><<<dim3((M6 + TM - 1) / TM, 640 / TN), 256, 0, stream>>>(
        cf, Wcomb, 128, cbias, exf, 640, M6, 128, 0, NS, c0);
    // scan this chunk
    scan2_kernel<<<BB, 512, 0, stream>>>(exf, pgbuf, mask, length, Wp1, Wp2,
                                         bp2, Whc, state, out, c0, NS,
                                         (c == 0) ? 1 : 0);
  }
}

// Round 5
// 5228.189 us; speedup vs baseline: 2.0090x; 1.1011x over previous
//
#include <hip/hip_runtime.h>
#include <hip/hip_bf16.h>
#include <cstdint>

// ---------------------------------------------------------------------------
// B=32, L=2048, E=256, H=128, C=128. Scan steps j=0..2046 (t=j+1).
// R5: scan3 — true register-resident weights (__launch_bounds__(512,2);
// R4's VGPR=120 proved the 160 weight floats were re-fetched from L2 every
// step), B+C merged into one wave-0 phase (serial in-lane sampling, fast
// math on the trajectory-neutral logp path), 4 -> 3 barriers, EXF park +
// prefetch hidden under sampling on waves 1-7.
// ---------------------------------------------------------------------------
static constexpr int BB   = 32;
static constexpr int LQ   = 2048;
static constexpr int NSTP = 2047;
static constexpr int EE   = 256;

__device__ __forceinline__ void bar_lds() {
  asm volatile("s_waitcnt lgkmcnt(0)\n\ts_barrier" ::: "memory");
}

// ---------------- Threefry-2x32 (JAX-compatible, verified by R3/R4 pass) ---
__device__ __forceinline__ uint32_t rotl32(uint32_t x, int d) {
  return (x << d) | (x >> (32 - d));
}
__device__ __forceinline__ void tf2x32(uint32_t k0, uint32_t k1,
                                       uint32_t x0, uint32_t x1,
                                       uint32_t& o0, uint32_t& o1) {
  uint32_t ks2 = k0 ^ k1 ^ 0x1BD11BDAu;
  x0 += k0; x1 += k1;
  x0+=x1; x1=rotl32(x1,13); x1^=x0;  x0+=x1; x1=rotl32(x1,15); x1^=x0;
  x0+=x1; x1=rotl32(x1,26); x1^=x0;  x0+=x1; x1=rotl32(x1, 6); x1^=x0;
  x0+=k1; x1+=ks2+1u;
  x0+=x1; x1=rotl32(x1,17); x1^=x0;  x0+=x1; x1=rotl32(x1,29); x1^=x0;
  x0+=x1; x1=rotl32(x1,16); x1^=x0;  x0+=x1; x1=rotl32(x1,24); x1^=x0;
  x0+=ks2; x1+=k0+2u;
  x0+=x1; x1=rotl32(x1,13); x1^=x0;  x0+=x1; x1=rotl32(x1,15); x1^=x0;
  x0+=x1; x1=rotl32(x1,26); x1^=x0;  x0+=x1; x1=rotl32(x1, 6); x1^=x0;
  x0+=k0; x1+=k1+3u;
  x0+=x1; x1=rotl32(x1,17); x1^=x0;  x0+=x1; x1=rotl32(x1,29); x1^=x0;
  x0+=x1; x1=rotl32(x1,16); x1^=x0;  x0+=x1; x1=rotl32(x1,24); x1^=x0;
  x0+=k1; x1+=ks2+4u;
  x0+=x1; x1=rotl32(x1,13); x1^=x0;  x0+=x1; x1=rotl32(x1,15); x1^=x0;
  x0+=x1; x1=rotl32(x1,26); x1^=x0;  x0+=x1; x1=rotl32(x1, 6); x1^=x0;
  x0+=ks2; x1+=k0+5u;
  o0 = x0; o1 = x1;
}

__device__ __forceinline__ float sigm(float x) { return 1.0f / (1.0f + expf(-x)); }

// ---------------- prep: Whc = Wih[:,128:]+Whh; Wcomb/cbias (P1|G1 fused) ---
__global__ void prep_kernel(const float* __restrict__ Wp1,
                            const float* __restrict__ bp1,
                            const float* __restrict__ Wih,
                            const float* __restrict__ Whh,
                            const float* __restrict__ bih,
                            const float* __restrict__ bhh,
                            float* __restrict__ Whc,
                            float* __restrict__ Wcomb,
                            float* __restrict__ cbias) {
  int tid = blockIdx.x * blockDim.x + threadIdx.x;
  int nt  = gridDim.x * blockDim.x;
  for (int p = tid; p < 512 * 128; p += nt) {
    int g = p >> 7, e = p & 127;
    Whc[p] = Wih[g * 256 + 128 + e] + Whh[p];
  }
  for (int p = tid; p < 640 * 128; p += nt) {
    int n = p >> 7, e = p & 127;
    Wcomb[p] = (n < 128) ? Wp1[n * 256 + e] : Wih[(n - 128) * 256 + e];
  }
  for (int n = tid; n < 640; n += nt)
    cbias[n] = (n < 128) ? bp1[n] : (bih[n - 128] + bhh[n - 128]);
}

// ---------------- precompute gumbel perturbations pg[j][b*6+k] -------------
__global__ void gumbel_kernel(float* __restrict__ pg) {
  int idx = blockIdx.x * blockDim.x + threadIdx.x;
  if (idx >= NSTP * 192) return;
  int j = idx / 192, r = idx % 192;
  uint32_t a0, a1, y0, y1;
  tf2x32(0u, 42u, 0u, (uint32_t)j, a0, a1);
  tf2x32(a0, a1, 0u, (uint32_t)r, y0, y1);
  uint32_t bits = y0 ^ y1;
  float f = __uint_as_float((bits >> 9) | 0x3f800000u) - 1.0f;
  float u = fmaxf(f, 1.17549435e-38f);
  double g = -log(-log((double)u));
  pg[idx] = (float)g;
}

// ---------------- fp32 GEMM (unchanged) ------------------------------------
#define TM 128
#define TN 128
#define TKK 8
template <int MODE>
__global__ __launch_bounds__(256) void gemm_kernel(
    const float* __restrict__ A, const float* __restrict__ Bm, int ldb,
    const float* __restrict__ bias, float* __restrict__ C, int ldc,
    int M, int K, int relu, int NS, int c0) {
  int m0 = blockIdx.x * TM;
  int n0 = blockIdx.y * TN;
  int tid = threadIdx.x;
  __shared__ float As[TKK][TM + 4];
  __shared__ float Bs[TKK][TN + 4];

  int srow = tid >> 1;
  int skq  = (tid & 1) * 4;
  int gm   = m0 + srow;
  bool mvalid = gm < M;
  const float* Arow;
  if (MODE == 1) {
    int gmc = mvalid ? gm : 0;
    int bb = gmc / NS, cs = gmc % NS;
    Arow = A + (size_t)(bb * (LQ + 2) + c0 + cs + 2) * EE;
  } else {
    Arow = A + (size_t)gm * K;
  }
  const float* Brow = Bm + (size_t)(n0 + srow) * ldb;

  float acc[8][8] = {};
  int tm = (tid >> 4) * 8;
  int tn = (tid & 15) * 8;

  for (int k0 = 0; k0 < K; k0 += TKK) {
    float4 av = mvalid ? *(const float4*)(Arow + k0 + skq)
                       : make_float4(0.f, 0.f, 0.f, 0.f);
    float4 bv = *(const float4*)(Brow + k0 + skq);
    __syncthreads();
    As[skq + 0][srow] = av.x; As[skq + 1][srow] = av.y;
    As[skq + 2][srow] = av.z; As[skq + 3][srow] = av.w;
    Bs[skq + 0][srow] = bv.x; Bs[skq + 1][srow] = bv.y;
    Bs[skq + 2][srow] = bv.z; Bs[skq + 3][srow] = bv.w;
    __syncthreads();
#pragma unroll
    for (int kk = 0; kk < TKK; kk++) {
      float4 a0 = *(const float4*)&As[kk][tm];
      float4 a1 = *(const float4*)&As[kk][tm + 4];
      float4 b0 = *(const float4*)&Bs[kk][tn];
      float4 b1 = *(const float4*)&Bs[kk][tn + 4];
      float aa[8] = {a0.x, a0.y, a0.z, a0.w, a1.x, a1.y, a1.z, a1.w};
      float bb2[8] = {b0.x, b0.y, b0.z, b0.w, b1.x, b1.y, b1.z, b1.w};
#pragma unroll
      for (int i = 0; i < 8; i++)
#pragma unroll
        for (int jx = 0; jx < 8; jx++) acc[i][jx] += aa[i] * bb2[jx];
    }
  }
#pragma unroll
  for (int i = 0; i < 8; i++) {
    int gm2 = m0 + tm + i;
    if (gm2 >= M) break;
#pragma unroll
    for (int jx = 0; jx < 8; jx++) {
      int gn = n0 + tn + jx;
      float v = acc[i][jx] + bias[gn];
      if (relu) v = fmaxf(v, 0.f);
      C[(size_t)gm2 * ldc + gn] = v;
    }
  }
}

// ---------------- scan v3: 3 phases/barriers per step ----------------------
// exf rows per (b,cs): 6 x [p1(128) | g1(512)] = 3840 floats.
// state: h[32*128] | c[32*128] | lp[32]
__global__ __launch_bounds__(512, 2) void scan3_kernel(
    const float* __restrict__ exf, const float* __restrict__ pg,
    const int* __restrict__ mask, const int* __restrict__ length,
    const float* __restrict__ Wp1, const float* __restrict__ Wp2,
    const float* __restrict__ bp2, const float* __restrict__ Whc,
    float* __restrict__ state, float* __restrict__ out,
    int c0, int NS, int init) {
  const int b = blockIdx.x;
  const int tid = threadIdx.x;
  const int q = tid & 3;        // h-quarter for phase-A dots
  const int gb = tid >> 2;      // 0..127

  __shared__ float EXF[2][3840];
  __shared__ float h_pad[144];      // quarters at stride 36 (bank-spread)
  __shared__ float hh_s[128];
  __shared__ float ghh_s[512];
  __shared__ float scv[8];
  __shared__ float wp2_lds[128];
  __shared__ float gum_lds[2][8];
  __shared__ int   msk_lds[2][8];
  __shared__ int   idx_s;
  __shared__ char  idxb[2048];

  // ---- weights into registers (resident: 512,2 -> 256-VGPR budget)
  float4 wp1r4[8], wv40[8], wv41[8], wv42[8], wv43[8];
  {
    const float4* s0 = (const float4*)(Wp1 + (size_t)gb * 256 + 128 + q * 32);
    const float4* a0 = (const float4*)(Whc + ((size_t)gb + 0) * 128 + q * 32);
    const float4* a1 = (const float4*)(Whc + ((size_t)gb + 128) * 128 + q * 32);
    const float4* a2 = (const float4*)(Whc + ((size_t)gb + 256) * 128 + q * 32);
    const float4* a3 = (const float4*)(Whc + ((size_t)gb + 384) * 128 + q * 32);
#pragma unroll
    for (int i = 0; i < 8; i++) {
      wp1r4[i] = s0[i];
      wv40[i] = a0[i]; wv41[i] = a1[i]; wv42[i] = a2[i]; wv43[i] = a3[i];
    }
  }
  const float bp2v = bp2[0];
  const int len_b = length[b];

  float c_r = 0.f, lp_r = 0.f;
  if (tid < 144) h_pad[tid] = 0.f;
  if (tid < 128) {
    if (!init) h_pad[(tid >> 5) * 36 + (tid & 31)] = state[b * 128 + tid];
    c_r = init ? 0.f : state[4096 + b * 128 + tid];
    wp2_lds[tid] = Wp2[tid];
  }
  if (tid == 0) lp_r = init ? 0.f : state[8192 + b];

  // ---- prologue: stage step 0; prefetch step 1 into regs
  float4 pf0, pf1, pf2;
  float pfg = 0.f; int pfm = 0;
  {
    const float4* e0 = (const float4*)(exf + (size_t)b * NS * 3840);
    ((float4*)EXF[0])[tid] = e0[tid];
    if (tid < 448) ((float4*)EXF[0])[512 + tid] = e0[512 + tid];
    if (tid < 6) {
      gum_lds[0][tid] = pg[(size_t)c0 * 192 + b * 6 + tid];
      msk_lds[0][tid] = mask[((size_t)b * LQ + c0 + 1) * 6 + tid];
    }
    int cs1 = (NS > 1) ? 1 : 0;
    const float4* e1 = (const float4*)(exf + ((size_t)b * NS + cs1) * 3840);
    if (tid >= 64) {
      int i0 = tid - 64;
      pf0 = e1[i0];
      pf1 = e1[448 + i0];
      if (tid < 128) pf2 = e1[896 + i0];
    }
    if (tid >= 384 && tid < 390)
      pfg = pg[(size_t)(c0 + cs1) * 192 + b * 6 + (tid - 384)];
    if (tid >= 390 && tid < 396)
      pfm = mask[((size_t)b * LQ + c0 + cs1 + 1) * 6 + (tid - 390)];
  }
  bar_lds();

  for (int cs = 0; cs < NS; ++cs) {
    const int buf = cs & 1;
    const int nb = buf ^ 1;

    // ---- phase A: h once from LDS; hid_h partial + 4 gate-h partials
    {
      const float4* hp4 = (const float4*)(h_pad + q * 36);
      float hidp = 0.f, p0 = 0.f, p1 = 0.f, p2 = 0.f, p3 = 0.f;
#pragma unroll
      for (int i = 0; i < 8; i++) {
        float4 hv = hp4[i];
        float4 w = wp1r4[i];
        hidp += w.x * hv.x + w.y * hv.y + w.z * hv.z + w.w * hv.w;
        float4 a = wv40[i];
        p0 += a.x * hv.x + a.y * hv.y + a.z * hv.z + a.w * hv.w;
        a = wv41[i];
        p1 += a.x * hv.x + a.y * hv.y + a.z * hv.z + a.w * hv.w;
        a = wv42[i];
        p2 += a.x * hv.x + a.y * hv.y + a.z * hv.z + a.w * hv.w;
        a = wv43[i];
        p3 += a.x * hv.x + a.y * hv.y + a.z * hv.z + a.w * hv.w;
      }
      hidp += __shfl_xor(hidp, 1); hidp += __shfl_xor(hidp, 2);
      p0 += __shfl_xor(p0, 1); p0 += __shfl_xor(p0, 2);
      p1 += __shfl_xor(p1, 1); p1 += __shfl_xor(p1, 2);
      p2 += __shfl_xor(p2, 1); p2 += __shfl_xor(p2, 2);
      p3 += __shfl_xor(p3, 1); p3 += __shfl_xor(p3, 2);
      if (q == 0) {
        hh_s[gb] = hidp;
        ghh_s[gb] = p0; ghh_s[128 + gb] = p1;
        ghh_s[256 + gb] = p2; ghh_s[384 + gb] = p3;
      }
    }
    bar_lds();

    // ---- phase BC: wave 0 scores+samples; waves 1-7 park & prefetch
    if (tid < 64) {
      const int k = tid >> 3, r = tid & 7;
      float s = 0.f;
      if (k < 6) {
        const float* pb = &EXF[buf][k * 640 + r * 16];
        const float* hb = &hh_s[r * 16];
        const float* wb = &wp2_lds[r * 16];
#pragma unroll
        for (int ii = 0; ii < 4; ii++) {
          float4 p = *(const float4*)(pb + ii * 4);
          float4 hh = *(const float4*)(hb + ii * 4);
          float4 w = *(const float4*)(wb + ii * 4);
          s += fmaxf(p.x + hh.x, 0.f) * w.x + fmaxf(p.y + hh.y, 0.f) * w.y +
               fmaxf(p.z + hh.z, 0.f) * w.z + fmaxf(p.w + hh.w, 0.f) * w.w;
        }
      }
      s += __shfl_xor(s, 1);
      s += __shfl_xor(s, 2);
      s += __shfl_xor(s, 4);
      if (k < 6 && r == 0) scv[k] = fmaxf(s + bp2v, 0.f);
      asm volatile("s_waitcnt lgkmcnt(0)" ::: "memory");
      if (tid == 0) {
        float best = -3.4e38f, mx = -1e9f, libest = -1e9f, ssum;
        int bi = 0;
        float lgv[6];
#pragma unroll
        for (int k2 = 0; k2 < 6; k2++) {
          float lg = msk_lds[buf][k2] ? scv[k2] : -1e9f;
          float pt = gum_lds[buf][k2] + lg;
          if (pt > best) { best = pt; bi = k2; libest = lg; }
          mx = fmaxf(mx, lg);
          lgv[k2] = lg;
        }
        ssum = 0.f;
#pragma unroll
        for (int k2 = 0; k2 < 6; k2++) ssum += __expf(lgv[k2] - mx);
        float logp = libest - mx - __logf(ssum);
        if (len_b > c0 + cs + 1) lp_r += logp;
        idx_s = bi;
        idxb[cs] = (char)bi;
      }
    } else {
      int i0 = tid - 64;
      ((float4*)EXF[nb])[i0] = pf0;
      ((float4*)EXF[nb])[448 + i0] = pf1;
      if (tid < 128) ((float4*)EXF[nb])[896 + i0] = pf2;
      if (tid >= 384 && tid < 390) gum_lds[nb][tid - 384] = pfg;
      if (tid >= 390 && tid < 396) msk_lds[nb][tid - 390] = pfm;
      int csp = (cs + 2 < NS) ? cs + 2 : NS - 1;
      const float4* en = (const float4*)(exf + ((size_t)b * NS + csp) * 3840);
      pf0 = en[i0];
      pf1 = en[448 + i0];
      if (tid < 128) pf2 = en[896 + i0];
      if (tid >= 384 && tid < 390)
        pfg = pg[(size_t)(c0 + csp) * 192 + b * 6 + (tid - 384)];
      if (tid >= 390 && tid < 396)
        pfm = mask[((size_t)b * LQ + c0 + csp + 1) * 6 + (tid - 390)];
    }
    bar_lds();

    // ---- phase D: LSTM pointwise (tid<128)
    if (tid < 128) {
      int base = idx_s * 640 + 128 + tid;
      float iv = EXF[buf][base] + ghh_s[tid];
      float fv = EXF[buf][base + 128] + ghh_s[128 + tid];
      float gg = EXF[buf][base + 256] + ghh_s[256 + tid];
      float ov = EXF[buf][base + 384] + ghh_s[384 + tid];
      float c2 = sigm(fv) * c_r + sigm(iv) * tanhf(gg);
      float h2 = sigm(ov) * tanhf(c2);
      c_r = c2;
      h_pad[(tid >> 5) * 36 + (tid & 31)] = h2;
    }
    bar_lds();
  }

  // ---- epilogue
  if (tid < 128) {
    state[b * 128 + tid] = h_pad[(tid >> 5) * 36 + (tid & 31)];
    state[4096 + b * 128 + tid] = c_r;
  }
  if (tid == 0) {
    state[8192 + b] = lp_r;
    out[b] = lp_r;
  }
  for (int i = tid; i < NS; i += 512)
    out[32 + (size_t)(c0 + i) * 32 + b] = (float)idxb[i];
}

__global__ void sentinel_kernel(float* out, int n, float val) {
  int i = blockIdx.x * blockDim.x + threadIdx.x;
  if (i < n) out[i] = val;
}

// ---------------------------------------------------------------------------
extern "C" void kernel_launch(void* const* d_in, const int* in_sizes, int n_in,
                              void* d_out, int out_size, void* d_ws,
                              size_t ws_size, hipStream_t stream) {
  const float* memory = (const float*)d_in[0];
  const int* mask = (const int*)d_in[1];     // bool delivered as int32
  const int* length = (const int*)d_in[2];
  const float* W1  = (const float*)d_in[3];
  const float* b1  = (const float*)d_in[4];
  const float* Wp1 = (const float*)d_in[5];
  const float* bp1 = (const float*)d_in[6];
  const float* Wp2 = (const float*)d_in[7];
  const float* bp2 = (const float*)d_in[8];
  const float* Wih = (const float*)d_in[9];
  const float* Whh = (const float*)d_in[10];
  const float* bih = (const float*)d_in[11];
  const float* bhh = (const float*)d_in[12];
  float* out = (float*)d_out;

  char* ws = (char*)d_ws;
  const size_t o_whc   = 0;                    // 512*128*4  = 262144
  const size_t o_wcomb = 262144;               // 640*128*4  = 327680
  const size_t o_cbias = 589824;               // 640*4      = 2560
  const size_t o_state = 592384;               // -> pad 36864
  const size_t o_pg    = 629248;               // 2047*192*4 = 1572096
  const size_t o_buf   = 2201344;              // chunk buffers

  const size_t per_cs = 32ull * (768 + 3840) * 4;  // 589824
  long long usable = (long long)ws_size - (long long)o_buf;
  int CS = (usable > 0) ? (int)(usable / (long long)per_cs) : 0;
  if (CS > NSTP) CS = NSTP;
  if (CS < 1) {
    float val = -100000.0f - (float)(ws_size >> 20);
    sentinel_kernel<<<(out_size + 255) / 256, 256, 0, stream>>>(out, out_size, val);
    return;
  }

  float* Whc   = (float*)(ws + o_whc);
  float* Wcomb = (float*)(ws + o_wcomb);
  float* cbias = (float*)(ws + o_cbias);
  float* state = (float*)(ws + o_state);
  float* pgbuf = (float*)(ws + o_pg);

  prep_kernel<<<64, 256, 0, stream>>>(Wp1, bp1, Wih, Whh, bih, bhh,
                                      Whc, Wcomb, cbias);
  gumbel_kernel<<<(NSTP * 192 + 255) / 256, 256, 0, stream>>>(pgbuf);

  int nchunks = (NSTP + CS - 1) / CS;
  for (int c = 0; c < nchunks; ++c) {
    int c0 = c * CS;
    int NS = (c0 + CS <= NSTP) ? CS : (NSTP - c0);
    int Mcf = 32 * NS;
    int M6  = Mcf * 6;

    float* cf  = (float*)(ws + o_buf);
    float* exf = cf + (size_t)Mcf * 768;

    // cf = relu(memory_rows @ W1^T + b1): M=32*NS, N=768, K=256
    gemm_kernel<1><<<dim3((Mcf + TM - 1) / TM, 768 / TN), 256, 0, stream>>>(
        memory, W1, 256, b1, cf, 768, Mcf, 256, 1, NS, c0);
    // exf = cf6 @ Wcomb^T + cbias: M=M6, N=640 (p1|g1), K=128
    gemm_kernel<0><<<dim3((M6 + TM - 1) / TM, 640 / TN), 256, 0, stream>>>(
        cf, Wcomb, 128, cbias, exf, 640, M6, 128, 0, NS, c0);
    // scan this chunk
    scan3_kernel<<<BB, 512, 0, stream>>>(exf, pgbuf, mask, length, Wp1, Wp2,
                                         bp2, Whc, state, out, c0, NS,
                                         (c == 0) ? 1 : 0);
  }
}

// Round 6
// 5199.500 us; speedup vs baseline: 2.0201x; 1.0055x over previous
//
#include <hip/hip_runtime.h>
#include <hip/hip_bf16.h>
#include <cstdint>

// ---------------------------------------------------------------------------
// B=32, L=2048, E=256, H=128, C=128. Scan steps j=0..2046 (t=j+1).
// R6: R5 + register-pinned weights. R5's VGPR=124 proved the compiler
// rematerialized all 160 weight floats from L2 every step (320 KB/block/step
// through L1 = the whole 2.1us step). asm-pin makes remat impossible.
// Arithmetic is bit-identical to R5 (absmax 0.0) — do not touch.
// ---------------------------------------------------------------------------
static constexpr int BB   = 32;
static constexpr int LQ   = 2048;
static constexpr int NSTP = 2047;
static constexpr int EE   = 256;

__device__ __forceinline__ void bar_lds() {
  asm volatile("s_waitcnt lgkmcnt(0)\n\ts_barrier" ::: "memory");
}
#define PIN4(v) asm volatile("" : "+v"((v).x), "+v"((v).y), "+v"((v).z), "+v"((v).w))

// ---------------- Threefry-2x32 (JAX-compatible, verified R3-R5) -----------
__device__ __forceinline__ uint32_t rotl32(uint32_t x, int d) {
  return (x << d) | (x >> (32 - d));
}
__device__ __forceinline__ void tf2x32(uint32_t k0, uint32_t k1,
                                       uint32_t x0, uint32_t x1,
                                       uint32_t& o0, uint32_t& o1) {
  uint32_t ks2 = k0 ^ k1 ^ 0x1BD11BDAu;
  x0 += k0; x1 += k1;
  x0+=x1; x1=rotl32(x1,13); x1^=x0;  x0+=x1; x1=rotl32(x1,15); x1^=x0;
  x0+=x1; x1=rotl32(x1,26); x1^=x0;  x0+=x1; x1=rotl32(x1, 6); x1^=x0;
  x0+=k1; x1+=ks2+1u;
  x0+=x1; x1=rotl32(x1,17); x1^=x0;  x0+=x1; x1=rotl32(x1,29); x1^=x0;
  x0+=x1; x1=rotl32(x1,16); x1^=x0;  x0+=x1; x1=rotl32(x1,24); x1^=x0;
  x0+=ks2; x1+=k0+2u;
  x0+=x1; x1=rotl32(x1,13); x1^=x0;  x0+=x1; x1=rotl32(x1,15); x1^=x0;
  x0+=x1; x1=rotl32(x1,26); x1^=x0;  x0+=x1; x1=rotl32(x1, 6); x1^=x0;
  x0+=k0; x1+=k1+3u;
  x0+=x1; x1=rotl32(x1,17); x1^=x0;  x0+=x1; x1=rotl32(x1,29); x1^=x0;
  x0+=x1; x1=rotl32(x1,16); x1^=x0;  x0+=x1; x1=rotl32(x1,24); x1^=x0;
  x0+=k1; x1+=ks2+4u;
  x0+=x1; x1=rotl32(x1,13); x1^=x0;  x0+=x1; x1=rotl32(x1,15); x1^=x0;
  x0+=x1; x1=rotl32(x1,26); x1^=x0;  x0+=x1; x1=rotl32(x1, 6); x1^=x0;
  x0+=ks2; x1+=k0+5u;
  o0 = x0; o1 = x1;
}

__device__ __forceinline__ float sigm(float x) { return 1.0f / (1.0f + expf(-x)); }

// ---------------- prep: Whc = Wih[:,128:]+Whh; Wcomb/cbias (P1|G1 fused) ---
__global__ void prep_kernel(const float* __restrict__ Wp1,
                            const float* __restrict__ bp1,
                            const float* __restrict__ Wih,
                            const float* __restrict__ Whh,
                            const float* __restrict__ bih,
                            const float* __restrict__ bhh,
                            float* __restrict__ Whc,
                            float* __restrict__ Wcomb,
                            float* __restrict__ cbias) {
  int tid = blockIdx.x * blockDim.x + threadIdx.x;
  int nt  = gridDim.x * blockDim.x;
  for (int p = tid; p < 512 * 128; p += nt) {
    int g = p >> 7, e = p & 127;
    Whc[p] = Wih[g * 256 + 128 + e] + Whh[p];
  }
  for (int p = tid; p < 640 * 128; p += nt) {
    int n = p >> 7, e = p & 127;
    Wcomb[p] = (n < 128) ? Wp1[n * 256 + e] : Wih[(n - 128) * 256 + e];
  }
  for (int n = tid; n < 640; n += nt)
    cbias[n] = (n < 128) ? bp1[n] : (bih[n - 128] + bhh[n - 128]);
}

// ---------------- precompute gumbel perturbations pg[j][b*6+k] -------------
__global__ void gumbel_kernel(float* __restrict__ pg) {
  int idx = blockIdx.x * blockDim.x + threadIdx.x;
  if (idx >= NSTP * 192) return;
  int j = idx / 192, r = idx % 192;
  uint32_t a0, a1, y0, y1;
  tf2x32(0u, 42u, 0u, (uint32_t)j, a0, a1);
  tf2x32(a0, a1, 0u, (uint32_t)r, y0, y1);
  uint32_t bits = y0 ^ y1;
  float f = __uint_as_float((bits >> 9) | 0x3f800000u) - 1.0f;
  float u = fmaxf(f, 1.17549435e-38f);
  double g = -log(-log((double)u));
  pg[idx] = (float)g;
}

// ---------------- fp32 GEMM (unchanged) ------------------------------------
#define TM 128
#define TN 128
#define TKK 8
template <int MODE>
__global__ __launch_bounds__(256) void gemm_kernel(
    const float* __restrict__ A, const float* __restrict__ Bm, int ldb,
    const float* __restrict__ bias, float* __restrict__ C, int ldc,
    int M, int K, int relu, int NS, int c0) {
  int m0 = blockIdx.x * TM;
  int n0 = blockIdx.y * TN;
  int tid = threadIdx.x;
  __shared__ float As[TKK][TM + 4];
  __shared__ float Bs[TKK][TN + 4];

  int srow = tid >> 1;
  int skq  = (tid & 1) * 4;
  int gm   = m0 + srow;
  bool mvalid = gm < M;
  const float* Arow;
  if (MODE == 1) {
    int gmc = mvalid ? gm : 0;
    int bb = gmc / NS, cs = gmc % NS;
    Arow = A + (size_t)(bb * (LQ + 2) + c0 + cs + 2) * EE;
  } else {
    Arow = A + (size_t)gm * K;
  }
  const float* Brow = Bm + (size_t)(n0 + srow) * ldb;

  float acc[8][8] = {};
  int tm = (tid >> 4) * 8;
  int tn = (tid & 15) * 8;

  for (int k0 = 0; k0 < K; k0 += TKK) {
    float4 av = mvalid ? *(const float4*)(Arow + k0 + skq)
                       : make_float4(0.f, 0.f, 0.f, 0.f);
    float4 bv = *(const float4*)(Brow + k0 + skq);
    __syncthreads();
    As[skq + 0][srow] = av.x; As[skq + 1][srow] = av.y;
    As[skq + 2][srow] = av.z; As[skq + 3][srow] = av.w;
    Bs[skq + 0][srow] = bv.x; Bs[skq + 1][srow] = bv.y;
    Bs[skq + 2][srow] = bv.z; Bs[skq + 3][srow] = bv.w;
    __syncthreads();
#pragma unroll
    for (int kk = 0; kk < TKK; kk++) {
      float4 a0 = *(const float4*)&As[kk][tm];
      float4 a1 = *(const float4*)&As[kk][tm + 4];
      float4 b0 = *(const float4*)&Bs[kk][tn];
      float4 b1 = *(const float4*)&Bs[kk][tn + 4];
      float aa[8] = {a0.x, a0.y, a0.z, a0.w, a1.x, a1.y, a1.z, a1.w};
      float bb2[8] = {b0.x, b0.y, b0.z, b0.w, b1.x, b1.y, b1.z, b1.w};
#pragma unroll
      for (int i = 0; i < 8; i++)
#pragma unroll
        for (int jx = 0; jx < 8; jx++) acc[i][jx] += aa[i] * bb2[jx];
    }
  }
#pragma unroll
  for (int i = 0; i < 8; i++) {
    int gm2 = m0 + tm + i;
    if (gm2 >= M) break;
#pragma unroll
    for (int jx = 0; jx < 8; jx++) {
      int gn = n0 + tn + jx;
      float v = acc[i][jx] + bias[gn];
      if (relu) v = fmaxf(v, 0.f);
      C[(size_t)gm2 * ldc + gn] = v;
    }
  }
}

// ---------------- scan v4: v3 + pinned weights -----------------------------
// exf rows per (b,cs): 6 x [p1(128) | g1(512)] = 3840 floats.
// state: h[32*128] | c[32*128] | lp[32]
__global__ __launch_bounds__(512, 2) void scan4_kernel(
    const float* __restrict__ exf, const float* __restrict__ pg,
    const int* __restrict__ mask, const int* __restrict__ length,
    const float* __restrict__ Wp1, const float* __restrict__ Wp2,
    const float* __restrict__ bp2, const float* __restrict__ Whc,
    float* __restrict__ state, float* __restrict__ out,
    int c0, int NS, int init) {
  const int b = blockIdx.x;
  const int tid = threadIdx.x;
  const int q = tid & 3;        // h-quarter for phase-A dots
  const int gb = tid >> 2;      // 0..127

  __shared__ float EXF[2][3840];
  __shared__ float h_pad[144];      // quarters at stride 36 (bank-spread)
  __shared__ float hh_s[128];
  __shared__ float ghh_s[512];
  __shared__ float scv[8];
  __shared__ float wp2_lds[128];
  __shared__ float gum_lds[2][8];
  __shared__ int   msk_lds[2][8];
  __shared__ int   idx_s;
  __shared__ char  idxb[2048];

  // ---- weights into registers, PINNED (opaque to remat)
  float4 wp1r4[8], wv40[8], wv41[8], wv42[8], wv43[8];
  {
    const float4* s0 = (const float4*)(Wp1 + (size_t)gb * 256 + 128 + q * 32);
    const float4* a0 = (const float4*)(Whc + ((size_t)gb + 0) * 128 + q * 32);
    const float4* a1 = (const float4*)(Whc + ((size_t)gb + 128) * 128 + q * 32);
    const float4* a2 = (const float4*)(Whc + ((size_t)gb + 256) * 128 + q * 32);
    const float4* a3 = (const float4*)(Whc + ((size_t)gb + 384) * 128 + q * 32);
#pragma unroll
    for (int i = 0; i < 8; i++) {
      wp1r4[i] = s0[i];
      wv40[i] = a0[i]; wv41[i] = a1[i]; wv42[i] = a2[i]; wv43[i] = a3[i];
      PIN4(wp1r4[i]);
      PIN4(wv40[i]); PIN4(wv41[i]); PIN4(wv42[i]); PIN4(wv43[i]);
    }
  }
  const float bp2v = bp2[0];
  const int len_b = length[b];

  float c_r = 0.f, lp_r = 0.f;
  if (tid < 144) h_pad[tid] = 0.f;
  if (tid < 128) {
    if (!init) h_pad[(tid >> 5) * 36 + (tid & 31)] = state[b * 128 + tid];
    c_r = init ? 0.f : state[4096 + b * 128 + tid];
    wp2_lds[tid] = Wp2[tid];
  }
  if (tid == 0) lp_r = init ? 0.f : state[8192 + b];

  // ---- prologue: stage step 0; prefetch step 1 into regs
  float4 pf0, pf1, pf2;
  float pfg = 0.f; int pfm = 0;
  {
    const float4* e0 = (const float4*)(exf + (size_t)b * NS * 3840);
    ((float4*)EXF[0])[tid] = e0[tid];
    if (tid < 448) ((float4*)EXF[0])[512 + tid] = e0[512 + tid];
    if (tid < 6) {
      gum_lds[0][tid] = pg[(size_t)c0 * 192 + b * 6 + tid];
      msk_lds[0][tid] = mask[((size_t)b * LQ + c0 + 1) * 6 + tid];
    }
    int cs1 = (NS > 1) ? 1 : 0;
    const float4* e1 = (const float4*)(exf + ((size_t)b * NS + cs1) * 3840);
    if (tid >= 64) {
      int i0 = tid - 64;
      pf0 = e1[i0];
      pf1 = e1[448 + i0];
      if (tid < 128) pf2 = e1[896 + i0];
    }
    if (tid >= 384 && tid < 390)
      pfg = pg[(size_t)(c0 + cs1) * 192 + b * 6 + (tid - 384)];
    if (tid >= 390 && tid < 396)
      pfm = mask[((size_t)b * LQ + c0 + cs1 + 1) * 6 + (tid - 390)];
  }
  bar_lds();

  for (int cs = 0; cs < NS; ++cs) {
    const int buf = cs & 1;
    const int nb = buf ^ 1;

    // ---- phase A: h once from LDS; hid_h partial + 4 gate-h partials
    {
      const float4* hp4 = (const float4*)(h_pad + q * 36);
      float hidp = 0.f, p0 = 0.f, p1 = 0.f, p2 = 0.f, p3 = 0.f;
#pragma unroll
      for (int i = 0; i < 8; i++) {
        float4 hv = hp4[i];
        float4 w = wp1r4[i];
        hidp += w.x * hv.x + w.y * hv.y + w.z * hv.z + w.w * hv.w;
        float4 a = wv40[i];
        p0 += a.x * hv.x + a.y * hv.y + a.z * hv.z + a.w * hv.w;
        a = wv41[i];
        p1 += a.x * hv.x + a.y * hv.y + a.z * hv.z + a.w * hv.w;
        a = wv42[i];
        p2 += a.x * hv.x + a.y * hv.y + a.z * hv.z + a.w * hv.w;
        a = wv43[i];
        p3 += a.x * hv.x + a.y * hv.y + a.z * hv.z + a.w * hv.w;
      }
      hidp += __shfl_xor(hidp, 1); hidp += __shfl_xor(hidp, 2);
      p0 += __shfl_xor(p0, 1); p0 += __shfl_xor(p0, 2);
      p1 += __shfl_xor(p1, 1); p1 += __shfl_xor(p1, 2);
      p2 += __shfl_xor(p2, 1); p2 += __shfl_xor(p2, 2);
      p3 += __shfl_xor(p3, 1); p3 += __shfl_xor(p3, 2);
      if (q == 0) {
        hh_s[gb] = hidp;
        ghh_s[gb] = p0; ghh_s[128 + gb] = p1;
        ghh_s[256 + gb] = p2; ghh_s[384 + gb] = p3;
      }
    }
    bar_lds();

    // ---- phase BC: wave 0 scores+samples; waves 1-7 park & prefetch
    if (tid < 64) {
      const int k = tid >> 3, r = tid & 7;
      float s = 0.f;
      if (k < 6) {
        const float* pb = &EXF[buf][k * 640 + r * 16];
        const float* hb = &hh_s[r * 16];
        const float* wb = &wp2_lds[r * 16];
#pragma unroll
        for (int ii = 0; ii < 4; ii++) {
          float4 p = *(const float4*)(pb + ii * 4);
          float4 hh = *(const float4*)(hb + ii * 4);
          float4 w = *(const float4*)(wb + ii * 4);
          s += fmaxf(p.x + hh.x, 0.f) * w.x + fmaxf(p.y + hh.y, 0.f) * w.y +
               fmaxf(p.z + hh.z, 0.f) * w.z + fmaxf(p.w + hh.w, 0.f) * w.w;
        }
      }
      s += __shfl_xor(s, 1);
      s += __shfl_xor(s, 2);
      s += __shfl_xor(s, 4);
      if (k < 6 && r == 0) scv[k] = fmaxf(s + bp2v, 0.f);
      asm volatile("s_waitcnt lgkmcnt(0)" ::: "memory");
      if (tid == 0) {
        float best = -3.4e38f, mx = -1e9f, libest = -1e9f, ssum;
        int bi = 0;
        float lgv[6];
#pragma unroll
        for (int k2 = 0; k2 < 6; k2++) {
          float lg = msk_lds[buf][k2] ? scv[k2] : -1e9f;
          float pt = gum_lds[buf][k2] + lg;
          if (pt > best) { best = pt; bi = k2; libest = lg; }
          mx = fmaxf(mx, lg);
          lgv[k2] = lg;
        }
        ssum = 0.f;
#pragma unroll
        for (int k2 = 0; k2 < 6; k2++) ssum += __expf(lgv[k2] - mx);
        float logp = libest - mx - __logf(ssum);
        if (len_b > c0 + cs + 1) lp_r += logp;
        idx_s = bi;
        idxb[cs] = (char)bi;
      }
    } else {
      int i0 = tid - 64;
      ((float4*)EXF[nb])[i0] = pf0;
      ((float4*)EXF[nb])[448 + i0] = pf1;
      if (tid < 128) ((float4*)EXF[nb])[896 + i0] = pf2;
      if (tid >= 384 && tid < 390) gum_lds[nb][tid - 384] = pfg;
      if (tid >= 390 && tid < 396) msk_lds[nb][tid - 390] = pfm;
      int csp = (cs + 2 < NS) ? cs + 2 : NS - 1;
      const float4* en = (const float4*)(exf + ((size_t)b * NS + csp) * 3840);
      pf0 = en[i0];
      pf1 = en[448 + i0];
      if (tid < 128) pf2 = en[896 + i0];
      if (tid >= 384 && tid < 390)
        pfg = pg[(size_t)(c0 + csp) * 192 + b * 6 + (tid - 384)];
      if (tid >= 390 && tid < 396)
        pfm = mask[((size_t)b * LQ + c0 + csp + 1) * 6 + (tid - 390)];
    }
    bar_lds();

    // ---- phase D: LSTM pointwise (tid<128)
    if (tid < 128) {
      int base = idx_s * 640 + 128 + tid;
      float iv = EXF[buf][base] + ghh_s[tid];
      float fv = EXF[buf][base + 128] + ghh_s[128 + tid];
      float gg = EXF[buf][base + 256] + ghh_s[256 + tid];
      float ov = EXF[buf][base + 384] + ghh_s[384 + tid];
      float c2 = sigm(fv) * c_r + sigm(iv) * tanhf(gg);
      float h2 = sigm(ov) * tanhf(c2);
      c_r = c2;
      h_pad[(tid >> 5) * 36 + (tid & 31)] = h2;
    }
    bar_lds();
  }

  // ---- epilogue
  if (tid < 128) {
    state[b * 128 + tid] = h_pad[(tid >> 5) * 36 + (tid & 31)];
    state[4096 + b * 128 + tid] = c_r;
  }
  if (tid == 0) {
    state[8192 + b] = lp_r;
    out[b] = lp_r;
  }
  for (int i = tid; i < NS; i += 512)
    out[32 + (size_t)(c0 + i) * 32 + b] = (float)idxb[i];
}

__global__ void sentinel_kernel(float* out, int n, float val) {
  int i = blockIdx.x * blockDim.x + threadIdx.x;
  if (i < n) out[i] = val;
}

// ---------------------------------------------------------------------------
extern "C" void kernel_launch(void* const* d_in, const int* in_sizes, int n_in,
                              void* d_out, int out_size, void* d_ws,
                              size_t ws_size, hipStream_t stream) {
  const float* memory = (const float*)d_in[0];
  const int* mask = (const int*)d_in[1];     // bool delivered as int32
  const int* length = (const int*)d_in[2];
  const float* W1  = (const float*)d_in[3];
  const float* b1  = (const float*)d_in[4];
  const float* Wp1 = (const float*)d_in[5];
  const float* bp1 = (const float*)d_in[6];
  const float* Wp2 = (const float*)d_in[7];
  const float* bp2 = (const float*)d_in[8];
  const float* Wih = (const float*)d_in[9];
  const float* Whh = (const float*)d_in[10];
  const float* bih = (const float*)d_in[11];
  const float* bhh = (const float*)d_in[12];
  float* out = (float*)d_out;

  char* ws = (char*)d_ws;
  const size_t o_whc   = 0;                    // 512*128*4  = 262144
  const size_t o_wcomb = 262144;               // 640*128*4  = 327680
  const size_t o_cbias = 589824;               // 640*4      = 2560
  const size_t o_state = 592384;               // -> pad 36864
  const size_t o_pg    = 629248;               // 2047*192*4 = 1572096
  const size_t o_buf   = 2201344;              // chunk buffers

  const size_t per_cs = 32ull * (768 + 3840) * 4;  // 589824
  long long usable = (long long)ws_size - (long long)o_buf;
  int CS = (usable > 0) ? (int)(usable / (long long)per_cs) : 0;
  if (CS > NSTP) CS = NSTP;
  if (CS < 1) {
    float val = -100000.0f - (float)(ws_size >> 20);
    sentinel_kernel<<<(out_size + 255) / 256, 256, 0, stream>>>(out, out_size, val);
    return;
  }

  float* Whc   = (float*)(ws + o_whc);
  float* Wcomb = (float*)(ws + o_wcomb);
  float* cbias = (float*)(ws + o_cbias);
  float* state = (float*)(ws + o_state);
  float* pgbuf = (float*)(ws + o_pg);

  prep_kernel<<<64, 256, 0, stream>>>(Wp1, bp1, Wih, Whh, bih, bhh,
                                      Whc, Wcomb, cbias);
  gumbel_kernel<<<(NSTP * 192 + 255) / 256, 256, 0, stream>>>(pgbuf);

  int nchunks = (NSTP + CS - 1) / CS;
  for (int c = 0; c < nchunks; ++c) {
    int c0 = c * CS;
    int NS = (c0 + CS <= NSTP) ? CS : (NSTP - c0);
    int Mcf = 32 * NS;
    int M6  = Mcf * 6;

    float* cf  = (float*)(ws + o_buf);
    float* exf = cf + (size_t)Mcf * 768;

    // cf = relu(memory_rows @ W1^T + b1): M=32*NS, N=768, K=256
    gemm_kernel<1><<<dim3((Mcf + TM - 1) / TM, 768 / TN), 256, 0, stream>>>(
        memory, W1, 256, b1, cf, 768, Mcf, 256, 1, NS, c0);
    // exf = cf6 @ Wcomb^T + cbias: M=M6, N=640 (p1|g1), K=128
    gemm_kernel<0><<<dim3((M6 + TM - 1) / TM, 640 / TN), 256, 0, stream>>>(
        cf, Wcomb, 128, cbias, exf, 640, M6, 128, 0, NS, c0);
    // scan this chunk
    scan4_kernel<<<BB, 512, 0, stream>>>(exf, pgbuf, mask, length, Wp1, Wp2,
                                         bp2, Whc, state, out, c0, NS,
                                         (c == 0) ? 1 : 0);
  }
}